// Round 5
// baseline (522.811 us; speedup 1.0000x reference)
//
#include <hip/hip_runtime.h>
#include <cstddef>

// B=4, L=1024 -> ROWS=4096; m=64; Dc=256; Dq=inner=512; H=8; DH=64.
// Restructured (exact in real arithmetic, bf16 MFMA for all projections):
//   Qk[r,h,c]  = 0.125 * sum_d (x@Wq)[r,hd] Wk[c,hd]
//   scores     = ctx . Qk ; softmax ; CA[r,h,c] = sum_m attn*ctx
//   out[r,o]   = sum_{h,c} CA[r,h,c] * Wvo[h,c,o] + bo,  Wvo = Wv_h @ Wo_h (precomputed)

typedef __attribute__((ext_vector_type(8))) short short8;
typedef __attribute__((ext_vector_type(4))) float float4v;

__device__ __forceinline__ short f2bf(float f) {
  unsigned u = __float_as_uint(f);
  return (short)((u + 0x7fffu + ((u >> 16) & 1u)) >> 16);
}
__device__ __forceinline__ float bf2f(short s) {
  return __uint_as_float(((unsigned)(unsigned short)s) << 16);
}

// Convert x, Wk, Wv to bf16. 2304 blocks x 256 thr x 4 elems.
__global__ __launch_bounds__(256) void k_cvt(const float* __restrict__ x,
                                             const float* __restrict__ Wk,
                                             const float* __restrict__ Wv,
                                             short* __restrict__ xb,
                                             short* __restrict__ Wkb,
                                             short* __restrict__ Wvb) {
  size_t i4 = ((size_t)blockIdx.x * 256 + threadIdx.x) * 4;
  const float* src; short* dst; size_t off;
  if (i4 < 2097152)       { src = x;  dst = xb;  off = i4; }
  else if (i4 < 2228224)  { src = Wk; dst = Wkb; off = i4 - 2097152; }
  else                    { src = Wv; dst = Wvb; off = i4 - 2228224; }
  float4 v = *(const float4*)(src + off);
  short4 o; o.x = f2bf(v.x); o.y = f2bf(v.y); o.z = f2bf(v.z); o.w = f2bf(v.w);
  *(short4*)(dst + off) = o;
}

// Transpose-convert 512x512 fp32 -> bf16: out[n*512+k] = in[k*512+n]. 1024 blocks.
__global__ __launch_bounds__(256) void k_tcvt(const float* __restrict__ in,
                                              short* __restrict__ out) {
  int id = blockIdx.x * 256 + threadIdx.x;
  int k = id >> 9, n = id & 511;
  out[(size_t)n * 512 + k] = f2bf(in[(size_t)k * 512 + n]);
}

// bf16 MFMA GEMM: C[m0.., n0..] = scale * A(m,k) x Bt(n,k) + bias.
// 128(M) x 64(N) block tile, 4 waves m-split (each 32x64 = 2x4 MFMA tiles), BK=64,
// register-prefetch double-staging. Head plumbing: hb = n0>>bShift;
//   aBase k-offset += hb*crossAK;  bBase = Bt + (n0&bMask)*ldb + hb*bHS.
// LDS strides 72 shorts (144 B): b128 groups (9*row+q) mod 8 -> conflict-free floor rate.
__global__ __launch_bounds__(256) void k_mm(const short* __restrict__ A,
                                            const short* __restrict__ Bt,
                                            const float* __restrict__ bias,
                                            void* __restrict__ C,
                                            int lda, int ldb, int ldc, int K,
                                            int bShift, int bMask, int bHS, int crossAK,
                                            float scale, int storeBF16) {
  __shared__ short As[128 * 72];   // 18.4 KB [m][k]
  __shared__ short Bs[64 * 72];    //  9.2 KB [n][k]
  int t = threadIdx.x;
  int n0 = blockIdx.x * 64, m0 = blockIdx.y * 128;
  int hb = n0 >> bShift;
  const short* aBase = A + (size_t)m0 * lda + (size_t)hb * crossAK;
  const short* bBase = Bt + (size_t)(n0 & bMask) * ldb + (size_t)hb * bHS;
  int w = t >> 6, l = t & 63;
  int li = l & 15, kq = l >> 4;
  float4v acc[2][4];
#pragma unroll
  for (int i = 0; i < 2; ++i)
#pragma unroll
    for (int j = 0; j < 4; ++j) acc[i][j] = (float4v){0.f, 0.f, 0.f, 0.f};
  uint4 pa[4], pb[2];
#pragma unroll
  for (int p = 0; p < 4; ++p) {
    int i = p * 256 + t, row = i >> 3, kq8 = i & 7;
    pa[p] = *(const uint4*)(aBase + (size_t)row * lda + kq8 * 8);
  }
#pragma unroll
  for (int p = 0; p < 2; ++p) {
    int i = p * 256 + t, row = i >> 3, kq8 = i & 7;
    pb[p] = *(const uint4*)(bBase + (size_t)row * ldb + kq8 * 8);
  }
  for (int k0 = 0; k0 < K; k0 += 64) {
    __syncthreads();
#pragma unroll
    for (int p = 0; p < 4; ++p) {
      int i = p * 256 + t, row = i >> 3, kq8 = i & 7;
      *(uint4*)&As[row * 72 + kq8 * 8] = pa[p];
    }
#pragma unroll
    for (int p = 0; p < 2; ++p) {
      int i = p * 256 + t, row = i >> 3, kq8 = i & 7;
      *(uint4*)&Bs[row * 72 + kq8 * 8] = pb[p];
    }
    __syncthreads();
    if (k0 + 64 < K) {
#pragma unroll
      for (int p = 0; p < 4; ++p) {
        int i = p * 256 + t, row = i >> 3, kq8 = i & 7;
        pa[p] = *(const uint4*)(aBase + (size_t)row * lda + (k0 + 64) + kq8 * 8);
      }
#pragma unroll
      for (int p = 0; p < 2; ++p) {
        int i = p * 256 + t, row = i >> 3, kq8 = i & 7;
        pb[p] = *(const uint4*)(bBase + (size_t)row * ldb + (k0 + 64) + kq8 * 8);
      }
    }
#pragma unroll
    for (int kk = 0; kk < 2; ++kk) {
      short8 af[2], bfr[4];
#pragma unroll
      for (int mi = 0; mi < 2; ++mi)
        af[mi] = *(const short8*)&As[(w * 32 + mi * 16 + li) * 72 + kk * 32 + kq * 8];
#pragma unroll
      for (int ni = 0; ni < 4; ++ni)
        bfr[ni] = *(const short8*)&Bs[(ni * 16 + li) * 72 + kk * 32 + kq * 8];
#pragma unroll
      for (int mi = 0; mi < 2; ++mi)
#pragma unroll
        for (int ni = 0; ni < 4; ++ni)
          acc[mi][ni] = __builtin_amdgcn_mfma_f32_16x16x32_bf16(af[mi], bfr[ni], acc[mi][ni], 0, 0, 0);
    }
  }
#pragma unroll
  for (int ni = 0; ni < 4; ++ni) {
    int col = n0 + ni * 16 + li;
    float bv = bias ? bias[col] : 0.f;
#pragma unroll
    for (int mi = 0; mi < 2; ++mi)
#pragma unroll
      for (int r = 0; r < 4; ++r) {
        int row = m0 + w * 32 + mi * 16 + kq * 4 + r;
        float v = fmaf(acc[mi][ni][r], scale, bv);
        if (storeBF16) ((short*)C)[(size_t)row * ldc + col] = f2bf(v);
        else           ((float*)C)[(size_t)row * ldc + col] = v;
      }
  }
}

// Fused per-row attention. c-split waves: wave w computes ALL 8 heads over c-quarter
// {kk*64 + w*16 .. +16 | kk=0..3}; partials reduced via LDS. LDS ~41.3 KB -> 3 blocks/CU.
__global__ __launch_bounds__(256) void k_attn(const float* __restrict__ ctx,
                                              const short* __restrict__ Qkb,
                                              const float* __restrict__ bias,
                                              const int* __restrict__ mask,
                                              short* __restrict__ CA) {
  __shared__ float ctxs[64 * 68];   // 17.4 KB chunk [m][c-sub 64]; 68/4=17 odd -> b128 conflict-free
  __shared__ float qks[2048];       // 8 KB [h*256+c]
  __shared__ float P[4 * 64 * 12];  // 12.3 KB partials [w][m*12+h]
  __shared__ float sw[64 * 12];     // 3 KB scores -> attn weights [m*12+h] (16B-aligned f4 pairs)
  __shared__ float bs[64];
  __shared__ int   ms[64];
  int t = threadIdx.x;
  int r = blockIdx.x;
  const float* ctxr = ctx + (size_t)r * 16384;

  {  // stage Qk bf16 -> fp32 (one uint4 = 8 bf16 per thread)
    uint4 q8 = *((const uint4*)(Qkb + (size_t)r * 2048) + t);
    const short* qs = (const short*)&q8;
    float4 lo, hi;
    lo.x = bf2f(qs[0]); lo.y = bf2f(qs[1]); lo.z = bf2f(qs[2]); lo.w = bf2f(qs[3]);
    hi.x = bf2f(qs[4]); hi.y = bf2f(qs[5]); hi.z = bf2f(qs[6]); hi.w = bf2f(qs[7]);
    *(float4*)(qks + t * 8)     = lo;
    *(float4*)(qks + t * 8 + 4) = hi;
  }
  if (t < 64) { bs[t] = bias[(size_t)r * 64 + t]; ms[t] = mask[(size_t)r * 64 + t]; }

  int m_ = t & 63, w = t >> 6;
  float s[8] = {};
  for (int kk = 0; kk < 4; ++kk) {
    __syncthreads();                 // kk=0 also covers qks/bs/ms
#pragma unroll
    for (int i = 0; i < 4; ++i) {
      int idx = t + i * 256;         // 0..1023 f4 slots (64 rows x 16)
      int mm = idx >> 4, c4 = idx & 15;
      float4 v = *(const float4*)(ctxr + mm * 256 + kk * 64 + c4 * 4);
      *(float4*)(ctxs + mm * 68 + c4 * 4) = v;
    }
    __syncthreads();
    const float* cp = ctxs + m_ * 68 + w * 16;
    const float* qb = qks + kk * 64 + w * 16;
#pragma unroll
    for (int c4 = 0; c4 < 4; ++c4) {
      float4 cv = *(const float4*)(cp + c4 * 4);
#pragma unroll
      for (int h = 0; h < 8; ++h) {
        float4 q = *(const float4*)(qb + h * 256 + c4 * 4);   // wave-uniform broadcast
        s[h] = fmaf(cv.x, q.x, fmaf(cv.y, q.y, fmaf(cv.z, q.z, fmaf(cv.w, q.w, s[h]))));
      }
    }
  }
  float* pp = P + w * 768 + m_ * 12;
  *(float4*)(pp)     = make_float4(s[0], s[1], s[2], s[3]);
  *(float4*)(pp + 4) = make_float4(s[4], s[5], s[6], s[7]);
  __syncthreads();
  {  // reduce partials: thread t -> h=t&7, m in {t>>3, t>>3+32}
    int h = t & 7, mb = t >> 3;
#pragma unroll
    for (int j = 0; j < 2; ++j) {
      int mm = mb + j * 32, o = mm * 12 + h;
      sw[o] = P[o] + P[768 + o] + P[1536 + o] + P[2304 + o];
    }
  }
  __syncthreads();
  // softmax: lane=token m_, wave w -> heads {w, w+4}
  float s0 = sw[m_ * 12 + w], s1 = sw[m_ * 12 + w + 4];
  bool valid = ms[m_] != 0;
  float b = bs[m_];
  s0 = valid ? s0 + b : -INFINITY;
  s1 = valid ? s1 + b : -INFINITY;
  float mx0 = s0, mx1 = s1;
#pragma unroll
  for (int o = 32; o > 0; o >>= 1) {
    mx0 = fmaxf(mx0, __shfl_xor(mx0, o, 64));
    mx1 = fmaxf(mx1, __shfl_xor(mx1, o, 64));
  }
  float e0 = __expf(s0 - mx0), e1 = __expf(s1 - mx1);
  float sm0 = e0, sm1 = e1;
#pragma unroll
  for (int o = 32; o > 0; o >>= 1) {
    sm0 += __shfl_xor(sm0, o, 64);
    sm1 += __shfl_xor(sm1, o, 64);
  }
  sw[m_ * 12 + w]     = e0 / sm0;   // same slots this thread read -> no extra barrier needed
  sw[m_ * 12 + w + 4] = e1 / sm1;
  __syncthreads();
  // CA[h,c] = sum_m attn[h,m] ctx[m,c]; lane = c (coalesced, L2-hot re-read)
  float acc[8] = {};
#pragma unroll 4
  for (int m = 0; m < 64; ++m) {
    float cv = ctxr[m * 256 + t];
    float4 w0 = *(const float4*)(sw + m * 12);       // broadcast, 16B-aligned
    float4 w1 = *(const float4*)(sw + m * 12 + 4);
    acc[0] = fmaf(w0.x, cv, acc[0]); acc[1] = fmaf(w0.y, cv, acc[1]);
    acc[2] = fmaf(w0.z, cv, acc[2]); acc[3] = fmaf(w0.w, cv, acc[3]);
    acc[4] = fmaf(w1.x, cv, acc[4]); acc[5] = fmaf(w1.y, cv, acc[5]);
    acc[6] = fmaf(w1.z, cv, acc[6]); acc[7] = fmaf(w1.w, cv, acc[7]);
  }
  short* car = CA + (size_t)r * 2048;
#pragma unroll
  for (int hh = 0; hh < 8; ++hh) car[hh * 256 + t] = f2bf(acc[hh]);
}

extern "C" void kernel_launch(void* const* d_in, const int* in_sizes, int n_in,
                              void* d_out, int out_size, void* d_ws, size_t ws_size,
                              hipStream_t stream) {
  const float* x    = (const float*)d_in[0];
  const float* ctx  = (const float*)d_in[1];
  const int*   mask = (const int*)d_in[2];
  const float* bias = (const float*)d_in[3];
  const float* Wq   = (const float*)d_in[4];
  const float* Wk   = (const float*)d_in[5];
  const float* Wv   = (const float*)d_in[6];
  const float* Wo   = (const float*)d_in[7];
  const float* bo   = (const float*)d_in[8];
  float* out = (float*)d_out;

  char* ws = (char*)d_ws;
  short* xb    = (short*)(ws);                                // 4 MB  [4096x512]
  short* Qb    = (short*)(ws + (4u << 20));                   // 4 MB  [4096x512]
  short* Qkb   = (short*)(ws + (8u << 20));                   // 16 MB [4096x2048] bf16
  short* CAb   = (short*)(ws + (24u << 20));                  // 16 MB [4096x2048] bf16
  short* WqTb  = (short*)(ws + (40u << 20));                  // 0.5 MB [512x512] (n,k)
  short* WoTb  = (short*)(ws + (40u << 20) + (512u << 10));   // 0.5 MB [512x512] (o,hd)
  short* Wkb   = (short*)(ws + (41u << 20));                  // 0.25 MB [256x512]
  short* Wvb   = (short*)(ws + (41u << 20) + (256u << 10));   // 0.25 MB [256x512]
  short* WvoTb = (short*)(ws + (42u << 20));                  // 2 MB  [512x2048] [o][h*256+c]

  hipLaunchKernelGGL(k_cvt,  dim3(2304), dim3(256), 0, stream, x, Wk, Wv, xb, Wkb, Wvb);
  hipLaunchKernelGGL(k_tcvt, dim3(1024), dim3(256), 0, stream, Wq, WqTb);
  hipLaunchKernelGGL(k_tcvt, dim3(1024), dim3(256), 0, stream, Wo, WoTb);
  // prep: WvoT[o, h*256+c] = sum_d WoT[o, h*64+d] * Wv[c, h*64+d]   (M=512, N=2048, K=64/head)
  hipLaunchKernelGGL(k_mm, dim3(32, 4), dim3(256), 0, stream,
                     WoTb, Wvb, (const float*)nullptr, WvoTb,
                     512, 512, 2048, 64, 8, 255, 64, 64, 1.0f, 1);
  // K1: Qb = xb @ WqT^T   (M=4096, N=512, K=512)
  hipLaunchKernelGGL(k_mm, dim3(8, 32), dim3(256), 0, stream,
                     xb, WqTb, (const float*)nullptr, Qb,
                     512, 512, 512, 512, 31, 0x7fffffff, 0, 0, 1.0f, 1);
  // K2: Qkb[r, h*256+c] = 0.125 * sum_d Qb[r,h*64+d] Wk[c,h*64+d]   (N=2048, K=64/head)
  hipLaunchKernelGGL(k_mm, dim3(32, 32), dim3(256), 0, stream,
                     Qb, Wkb, (const float*)nullptr, Qkb,
                     512, 512, 2048, 64, 8, 255, 64, 64, 0.125f, 1);
  // attention
  hipLaunchKernelGGL(k_attn, dim3(4096), dim3(256), 0, stream, ctx, Qkb, bias, mask, CAb);
  // final: out = CAb @ WvoT^T + bo   (M=4096, N=512, K=2048)
  hipLaunchKernelGGL(k_mm, dim3(8, 32), dim3(256), 0, stream,
                     CAb, WvoTb, bo, out,
                     2048, 2048, 512, 2048, 31, 0x7fffffff, 0, 0, 1.0f, 0);
}